// Round 8
// baseline (269.968 us; speedup 1.0000x reference)
//
#include <hip/hip_runtime.h>
#include <cstdint>
#include <cstddef>

// Problem dims
#define Bb 2
#define Ss 2048
#define Dd 1024
#define Hh 16
#define DKk 64

typedef unsigned short ushort_t;
typedef __bf16 bf16x8 __attribute__((ext_vector_type(8)));
typedef __bf16 bf16x4 __attribute__((ext_vector_type(4)));
typedef short s16x4 __attribute__((ext_vector_type(4)));
typedef float f32x4 __attribute__((ext_vector_type(4)));
typedef unsigned short us8 __attribute__((ext_vector_type(8)));
typedef unsigned short us4 __attribute__((ext_vector_type(4)));

__device__ __forceinline__ ushort_t f2bf(float f) {
  __bf16 h = (__bf16)f;
  return __builtin_bit_cast(unsigned short, h);
}

// v_mfma_f32_16x16x16_bf16 accumulate: c += a*b  (A/B: 4 bf16/lane).
// Builtin, not inline asm: the compiler's hazard recognizer inserts the
// mandatory VALU->MFMA / MFMA->VALU wait states only for intrinsics
// (rounds 4/5 failed from an asm MFMA adjacent to VALU). Body guarded by
// __HIP_DEVICE_COMPILE__: the builtin doesn't exist in the host pass
// (round-7 compile failure), and this function is device-only anyway.
__device__ __forceinline__ void mfma16(f32x4& c, bf16x4 a, bf16x4 b) {
#if defined(__HIP_DEVICE_COMPILE__)
  c = __builtin_amdgcn_mfma_f32_16x16x16bf16_1k(
      __builtin_bit_cast(s16x4, a), __builtin_bit_cast(s16x4, b), c, 0, 0, 0);
#else
  (void)a; (void)b; (void)c;  // host stub, never executed
#endif
}

// global -> LDS direct copy, 16B per lane. LDS dest must be wave-uniform;
// HW writes lane l's data at ldsbase + l*16.
__device__ __forceinline__ void gload_lds16(const void* g, void* l) {
  __builtin_amdgcn_global_load_lds(
      (__attribute__((address_space(1))) void*)(g),
      (__attribute__((address_space(3))) void*)(l),
      16, 0, 0);
}

// ---------------------------------------------------------------- cast fp32->bf16
__global__ __launch_bounds__(256) void cast_k(const float* __restrict__ s,
                                              ushort_t* __restrict__ d, int n8) {
  const int i = blockIdx.x * 256 + threadIdx.x;
  if (i >= n8) return;
  const float4* sp = (const float4*)s;
  float4 a = sp[2 * i], b = sp[2 * i + 1];
  us8 o;
  o[0] = f2bf(a.x); o[1] = f2bf(a.y); o[2] = f2bf(a.z); o[3] = f2bf(a.w);
  o[4] = f2bf(b.x); o[5] = f2bf(b.y); o[6] = f2bf(b.z); o[7] = f2bf(b.w);
  ((us8*)d)[i] = o;
}

// ---------------------------------------------------------------- GEMM
// y[m][n] = sum_k A[m][k] * W[n][k]  (both row-major, K contiguous)
// MODE 0: QKV projection. N=3072 (wq|wk|wv packed). Epilogue adds bias,
//         scales Q by 0.125*log2(e) (attn softmax runs in exp2 domain),
//         writes Q,K as [b,h,s,dk] bf16 and V transposed as VT [b,h,dk,s].
// MODE 1: output projection. N=1024. Epilogue adds bias, writes fp32 [m][n].
template <int MODE>
__global__ __launch_bounds__(256) void gemm_k(
    const ushort_t* __restrict__ A, const ushort_t* __restrict__ W,
    const float* __restrict__ b0, const float* __restrict__ b1,
    const float* __restrict__ b2,
    ushort_t* __restrict__ oQ, ushort_t* __restrict__ oK,
    ushort_t* __restrict__ oVT, float* __restrict__ oF) {
  constexpr int Kd = 1024;
  __shared__ ushort_t As[128 * 32];
  __shared__ ushort_t Bs[128 * 32];
  const int tid = threadIdx.x;
  const int lane = tid & 63;
  const int wave = tid >> 6;
  const int m0 = blockIdx.y * 128;
  const int n0 = blockIdx.x * 128;
  const int lr = lane & 15;
  const int lg = lane >> 4;
  const int srow = lane >> 2;        // staging row within 16-row segment
  const int scol = (lane & 3) * 8;   // staging col (elements)
  const int ar = (wave >> 1) * 64;   // wave's output row base in tile
  const int bc = (wave & 1) * 64;    // wave's output col base in tile

  f32x4 acc[4][4] = {};

  for (int kt = 0; kt < Kd / 32; ++kt) {
    const int k0 = kt * 32;
#pragma unroll
    for (int c = 0; c < 2; ++c) {
      const int seg = wave * 2 + c;  // 0..7, 16 rows (1KB) each
      const int row = seg * 16 + srow;
      gload_lds16(A + (size_t)(m0 + row) * Kd + k0 + scol, (char*)As + seg * 1024);
      gload_lds16(W + (size_t)(n0 + row) * Kd + k0 + scol, (char*)Bs + seg * 1024);
    }
    __syncthreads();  // drains vmcnt before barrier
    bf16x8 af[4], bfr[4];
#pragma unroll
    for (int i = 0; i < 4; ++i)
      af[i] = *(const bf16x8*)&As[(ar + i * 16 + lr) * 32 + lg * 8];
#pragma unroll
    for (int j = 0; j < 4; ++j)
      bfr[j] = *(const bf16x8*)&Bs[(bc + j * 16 + lr) * 32 + lg * 8];
#pragma unroll
    for (int i = 0; i < 4; ++i)
#pragma unroll
      for (int j = 0; j < 4; ++j)
        acc[i][j] = __builtin_amdgcn_mfma_f32_16x16x32_bf16(af[i], bfr[j],
                                                            acc[i][j], 0, 0, 0);
    __syncthreads();
  }

  // Epilogue. C/D layout: reg r -> row (lg*4 + r), col = lr  [m89-verified]
#pragma unroll
  for (int i = 0; i < 4; ++i) {
    const int mrow = m0 + ar + i * 16 + lg * 4;  // + r
#pragma unroll
    for (int j = 0; j < 4; ++j) {
      const int n = n0 + bc + j * 16 + lr;
      if (MODE == 0) {
        const int sel = n >> 10;       // 0=Q 1=K 2=V (uniform per j)
        const int nn = n & 1023;
        const float bias = (sel == 0 ? b0 : sel == 1 ? b1 : b2)[nn];
        const int h = nn >> 6, dk = nn & 63;
        const int bidx = mrow >> 11;
        const int s = mrow & 2047;     // rows s..s+3 stay in same batch
        const int bh = bidx * Hh + h;
        if (sel == 2) {
          // V transposed: VT[bh][dk][s], 4 consecutive s -> one 8B store
          us4 pk;
#pragma unroll
          for (int r = 0; r < 4; ++r) pk[r] = f2bf(acc[i][j][r] + bias);
          *(us4*)&oVT[((size_t)bh * DKk + dk) * Ss + s] = pk;
        } else {
          ushort_t* dst = (sel == 0) ? oQ : oK;
          // Q: fold 1/sqrt(DK) * log2(e) so attn uses raw v_exp (exp2)
          const float mul = (sel == 0) ? 0.1803368842f : 1.0f;
#pragma unroll
          for (int r = 0; r < 4; ++r)
            dst[((size_t)bh * Ss + (s + r)) * DKk + dk] =
                f2bf((acc[i][j][r] + bias) * mul);
        }
      } else {
        const float bias = b0[n];
#pragma unroll
        for (int r = 0; r < 4; ++r)
          oF[(size_t)(mrow + r) * Dd + n] = acc[i][j][r] + bias;
      }
    }
  }
}

// ---------------------------------------------------------------- flash attention
// Barrier-free: each wave owns 16 q-rows and walks its KV stream fully
// independently. K fragments are read straight from global into registers
// (per-XCD KV set = 4 heads x 512KB = 2MB, L2-resident with bh = bx&31);
// no LDS, no __syncthreads anywhere. Latency hidden by 4 waves/SIMD
// (VGPR <= 128 via launch_bounds) instead of a pipelined stage.
//
// Swapped-operand scheme (round-6-verified): QK^T computed as mfma(K,Q) ->
// D = S^T with q = lane&15; softmax state is one scalar per lane (in-lane
// tree + 2 shfl_xor). P stays in registers: exp2 -> bf16 casts -> bf16x4 IS
// the B-fragment of v_mfma_f32_16x16x16_bf16. PV accumulates O^T[d][q].
// Heavy q-tiles first (qt = 127 - ...): longest waves start earliest.
__global__ __launch_bounds__(128, 4) void attn_k(const ushort_t* __restrict__ Qg,
                                                 const ushort_t* __restrict__ Kg,
                                                 const ushort_t* __restrict__ Vt,
                                                 ushort_t* __restrict__ AO) {
  const int tid = threadIdx.x, lane = tid & 63, wave = tid >> 6;
  const int bx = blockIdx.x;
  const int bh = bx & 31;                    // bh&7 == XCD under round-robin
  const int qidx = bx >> 5;                  // 0..63
  const int qt = 127 - (qidx * 2 + wave);    // q-tile of 16 rows, heavy first
  const int lr = lane & 15, lg = lane >> 4;
  const ushort_t* Qp = Qg + (size_t)bh * Ss * DKk;
  const ushort_t* Kp = Kg + (size_t)bh * Ss * DKk;
  const ushort_t* Vp = Vt + (size_t)bh * DKk * Ss;
  const int q0 = qt * 16;
  const int nt = (qt >> 2) + 1;              // KV tiles of 64
  const int dct = qt & 3;                    // diagonal k-subtile index

  // Q fragment (B-operand of 16x16x32): row q0+lr, d = ks*32 + lg*8 ..+8
  bf16x8 qf[2];
#pragma unroll
  for (int ks = 0; ks < 2; ++ks)
    qf[ks] = *(const bf16x8*)&Qp[(size_t)(q0 + lr) * DKk + ks * 32 + lg * 8];

  f32x4 o[4] = {};   // O^T: o[dj][r] = O[q=lr][d = dj*16 + lg*4 + r]
  float m_ = -3e38f, l_ = 0.f;

  for (int t = 0; t < nt; ++t) {
    const int j0 = t * 64;
    const bool diag = (t == nt - 1);
    const int nct = diag ? dct + 1 : 4;

    // K fragments (A-operand of 16x16x32) straight from global:
    // row j0+ct*16+lr, k = ks*32 + lg*8 ..+8 (16B coalesced per lane)
    bf16x8 kf[4][2];
#pragma unroll
    for (int ct = 0; ct < 4; ++ct)
      if (ct < nct)
#pragma unroll
        for (int ks = 0; ks < 2; ++ks)
          kf[ct][ks] = *(const bf16x8*)&Kp[(size_t)(j0 + ct * 16 + lr) * DKk +
                                           ks * 32 + lg * 8];

    // ---- S^T = K Q^T : sc[ct][r] = S[q=lr][k = ct*16 + lg*4 + r]
    f32x4 sc[4];
#pragma unroll
    for (int ct = 0; ct < 4; ++ct) {
      if (ct < nct) {
        f32x4 z = {};
        z = __builtin_amdgcn_mfma_f32_16x16x32_bf16(kf[ct][0], qf[0], z, 0, 0, 0);
        z = __builtin_amdgcn_mfma_f32_16x16x32_bf16(kf[ct][1], qf[1], z, 0, 0, 0);
        sc[ct] = z;
      }
    }

    // VT fragments (A-operand of 16x16x16): row d=dj*16+lr, s=j0+ct*16+lg*4.
    // Issued after QK so the softmax chain below hides their L2 latency.
    bf16x4 vt4[4][4];
#pragma unroll
    for (int ct = 0; ct < 4; ++ct)
      if (ct < nct)
#pragma unroll
        for (int dj = 0; dj < 4; ++dj)
          vt4[dj][ct] = *(const bf16x4*)&Vp[(size_t)(dj * 16 + lr) * Ss + j0 +
                                            ct * 16 + lg * 4];

    // causal element mask: only the diagonal 16x16 sub-tile
    if (diag) {
#pragma unroll
      for (int r = 0; r < 4; ++r)
        if (lg * 4 + r > lr) sc[dct][r] = -1e30f;
    }

    // ---- online softmax, exp2 domain, per-lane scalar state (q = lr)
    float mx = -3e38f;
#pragma unroll
    for (int ct = 0; ct < 4; ++ct)
      if (ct < nct)
#pragma unroll
        for (int r = 0; r < 4; ++r) mx = fmaxf(mx, sc[ct][r]);
    mx = fmaxf(mx, __shfl_xor(mx, 16, 64));
    mx = fmaxf(mx, __shfl_xor(mx, 32, 64));
    const float mnew = fmaxf(m_, mx);
    const float fs = __builtin_exp2f(m_ - mnew);
    m_ = mnew;
    float ls = 0.f;
    bf16x4 pb[4];
#pragma unroll
    for (int ct = 0; ct < 4; ++ct) {
      if (ct < nct) {
        float p0 = __builtin_exp2f(sc[ct][0] - mnew);
        float p1 = __builtin_exp2f(sc[ct][1] - mnew);
        float p2 = __builtin_exp2f(sc[ct][2] - mnew);
        float p3 = __builtin_exp2f(sc[ct][3] - mnew);
        ls += (p0 + p1) + (p2 + p3);
        bf16x4 pbv;
        pbv[0] = (__bf16)p0;
        pbv[1] = (__bf16)p1;
        pbv[2] = (__bf16)p2;
        pbv[3] = (__bf16)p3;
        pb[ct] = pbv;
      }
    }
    ls += __shfl_xor(ls, 16, 64);
    ls += __shfl_xor(ls, 32, 64);
    l_ = l_ * fs + ls;
#pragma unroll
    for (int dj = 0; dj < 4; ++dj)
#pragma unroll
      for (int r = 0; r < 4; ++r) o[dj][r] *= fs;

    // ---- O^T += V^T P^T
    __builtin_amdgcn_s_setprio(1);
#pragma unroll
    for (int dj = 0; dj < 4; ++dj)
#pragma unroll
      for (int ct = 0; ct < 4; ++ct)
        if (ct < nct) mfma16(o[dj], vt4[dj][ct], pb[ct]);
    __builtin_amdgcn_s_setprio(0);
  }

  // ---- normalize and write AO [b*S+s][h*64+d] bf16 (8B packed over d)
  const int bb = bh >> 4, hh = bh & 15;
  const float inv = 1.0f / l_;
#pragma unroll
  for (int dj = 0; dj < 4; ++dj) {
    us4 pk;
#pragma unroll
    for (int r = 0; r < 4; ++r) pk[r] = f2bf(o[dj][r] * inv);
    *(us4*)&AO[((size_t)bb * Ss + q0 + lr) * Dd + hh * 64 + dj * 16 + lg * 4] =
        pk;
  }
}

// ---------------------------------------------------------------- launch
extern "C" void kernel_launch(void* const* d_in, const int* in_sizes, int n_in,
                              void* d_out, int out_size, void* d_ws, size_t ws_size,
                              hipStream_t stream) {
  const float* x  = (const float*)d_in[0];
  // d_in[1] = causal mask (tril) — hardcoded in attn kernel
  const float* wq = (const float*)d_in[2];
  const float* bq = (const float*)d_in[3];
  const float* wk = (const float*)d_in[4];
  const float* bk = (const float*)d_in[5];
  const float* wv = (const float*)d_in[6];
  const float* bv = (const float*)d_in[7];
  const float* wo = (const float*)d_in[8];
  const float* bo = (const float*)d_in[9];

  ushort_t* ws   = (ushort_t*)d_ws;
  ushort_t* xb   = ws;                   // [4096][1024] bf16 (8MB), reused as AO
  ushort_t* wqkv = xb + 4096 * 1024;     // [3072][1024] bf16 (6MB)
  ushort_t* wob  = wqkv + 3072 * 1024;   // [1024][1024] bf16 (2MB)
  ushort_t* Qb   = wob + 1024 * 1024;    // [2,16,2048,64] bf16 (8MB)
  ushort_t* Kb   = Qb + 4194304;         // (8MB)
  ushort_t* VTb  = Kb + 4194304;         // [2,16,64,2048] bf16 (8MB)
  ushort_t* AOb  = xb;                   // reuse: x dead after QKV GEMM

  cast_k<<<2048, 256, 0, stream>>>(x, xb, 524288);
  cast_k<<<512, 256, 0, stream>>>(wq, wqkv, 131072);
  cast_k<<<512, 256, 0, stream>>>(wk, wqkv + 1048576, 131072);
  cast_k<<<512, 256, 0, stream>>>(wv, wqkv + 2097152, 131072);
  cast_k<<<512, 256, 0, stream>>>(wo, wob, 131072);

  gemm_k<0><<<dim3(24, 32), 256, 0, stream>>>(xb, wqkv, bq, bk, bv, Qb, Kb, VTb,
                                              nullptr);
  attn_k<<<2048, 128, 0, stream>>>(Qb, Kb, VTb, AOb);
  gemm_k<1><<<dim3(8, 32), 256, 0, stream>>>(AOb, wob, bo, nullptr, nullptr,
                                             nullptr, nullptr, nullptr,
                                             (float*)d_out);
}

// Round 9
// 202.062 us; speedup vs baseline: 1.3361x; 1.3361x over previous
//
#include <hip/hip_runtime.h>
#include <cstdint>
#include <cstddef>

// Problem dims
#define Bb 2
#define Ss 2048
#define Dd 1024
#define Hh 16
#define DKk 64

typedef unsigned short ushort_t;
typedef __bf16 bf16x8 __attribute__((ext_vector_type(8)));
typedef __bf16 bf16x4 __attribute__((ext_vector_type(4)));
typedef short s16x4 __attribute__((ext_vector_type(4)));
typedef float f32x4 __attribute__((ext_vector_type(4)));
typedef unsigned short us8 __attribute__((ext_vector_type(8)));
typedef unsigned short us4 __attribute__((ext_vector_type(4)));

__device__ __forceinline__ ushort_t f2bf(float f) {
  __bf16 h = (__bf16)f;
  return __builtin_bit_cast(unsigned short, h);
}

// v_mfma_f32_16x16x16_bf16 accumulate: c += a*b  (A/B: 4 bf16/lane).
// Builtin, not inline asm: the compiler's hazard recognizer inserts the
// mandatory VALU->MFMA / MFMA->VALU wait states only for intrinsics
// (rounds 4/5 failed from an asm MFMA adjacent to VALU). Body guarded by
// __HIP_DEVICE_COMPILE__: the builtin doesn't exist in the host pass.
__device__ __forceinline__ void mfma16(f32x4& c, bf16x4 a, bf16x4 b) {
#if defined(__HIP_DEVICE_COMPILE__)
  c = __builtin_amdgcn_mfma_f32_16x16x16bf16_1k(
      __builtin_bit_cast(s16x4, a), __builtin_bit_cast(s16x4, b), c, 0, 0, 0);
#else
  (void)a; (void)b; (void)c;  // host stub, never executed
#endif
}

// global -> LDS direct copy, 16B per lane. LDS dest must be wave-uniform;
// HW writes lane l's data at ldsbase + l*16.
__device__ __forceinline__ void gload_lds16(const void* g, void* l) {
  __builtin_amdgcn_global_load_lds(
      (__attribute__((address_space(1))) void*)(g),
      (__attribute__((address_space(3))) void*)(l),
      16, 0, 0);
}

// ---------------------------------------------------------------- cast fp32->bf16
__global__ __launch_bounds__(256) void cast_k(const float* __restrict__ s,
                                              ushort_t* __restrict__ d, int n8) {
  const int i = blockIdx.x * 256 + threadIdx.x;
  if (i >= n8) return;
  const float4* sp = (const float4*)s;
  float4 a = sp[2 * i], b = sp[2 * i + 1];
  us8 o;
  o[0] = f2bf(a.x); o[1] = f2bf(a.y); o[2] = f2bf(a.z); o[3] = f2bf(a.w);
  o[4] = f2bf(b.x); o[5] = f2bf(b.y); o[6] = f2bf(b.z); o[7] = f2bf(b.w);
  ((us8*)d)[i] = o;
}

// ---------------------------------------------------------------- GEMM
// y[m][n] = sum_k A[m][k] * W[n][k]  (both row-major, K contiguous)
// MODE 0: QKV projection. N=3072 (wq|wk|wv packed). Epilogue adds bias,
//         scales Q by 0.125*log2(e) (attn softmax runs in exp2 domain),
//         writes Q,K as [b,h,s,dk] bf16 and V transposed as VT [b,h,dk,s].
// MODE 1: output projection. N=1024. Epilogue adds bias, writes fp32 [m][n].
template <int MODE>
__global__ __launch_bounds__(256) void gemm_k(
    const ushort_t* __restrict__ A, const ushort_t* __restrict__ W,
    const float* __restrict__ b0, const float* __restrict__ b1,
    const float* __restrict__ b2,
    ushort_t* __restrict__ oQ, ushort_t* __restrict__ oK,
    ushort_t* __restrict__ oVT, float* __restrict__ oF) {
  constexpr int Kd = 1024;
  __shared__ ushort_t As[128 * 32];
  __shared__ ushort_t Bs[128 * 32];
  const int tid = threadIdx.x;
  const int lane = tid & 63;
  const int wave = tid >> 6;
  const int m0 = blockIdx.y * 128;
  const int n0 = blockIdx.x * 128;
  const int lr = lane & 15;
  const int lg = lane >> 4;
  const int srow = lane >> 2;        // staging row within 16-row segment
  const int scol = (lane & 3) * 8;   // staging col (elements)
  const int ar = (wave >> 1) * 64;   // wave's output row base in tile
  const int bc = (wave & 1) * 64;    // wave's output col base in tile

  f32x4 acc[4][4] = {};

  for (int kt = 0; kt < Kd / 32; ++kt) {
    const int k0 = kt * 32;
#pragma unroll
    for (int c = 0; c < 2; ++c) {
      const int seg = wave * 2 + c;  // 0..7, 16 rows (1KB) each
      const int row = seg * 16 + srow;
      gload_lds16(A + (size_t)(m0 + row) * Kd + k0 + scol, (char*)As + seg * 1024);
      gload_lds16(W + (size_t)(n0 + row) * Kd + k0 + scol, (char*)Bs + seg * 1024);
    }
    __syncthreads();  // drains vmcnt before barrier
    bf16x8 af[4], bfr[4];
#pragma unroll
    for (int i = 0; i < 4; ++i)
      af[i] = *(const bf16x8*)&As[(ar + i * 16 + lr) * 32 + lg * 8];
#pragma unroll
    for (int j = 0; j < 4; ++j)
      bfr[j] = *(const bf16x8*)&Bs[(bc + j * 16 + lr) * 32 + lg * 8];
#pragma unroll
    for (int i = 0; i < 4; ++i)
#pragma unroll
      for (int j = 0; j < 4; ++j)
        acc[i][j] = __builtin_amdgcn_mfma_f32_16x16x32_bf16(af[i], bfr[j],
                                                            acc[i][j], 0, 0, 0);
    __syncthreads();
  }

  // Epilogue. C/D layout: reg r -> row (lg*4 + r), col = lr  [m89-verified]
#pragma unroll
  for (int i = 0; i < 4; ++i) {
    const int mrow = m0 + ar + i * 16 + lg * 4;  // + r
#pragma unroll
    for (int j = 0; j < 4; ++j) {
      const int n = n0 + bc + j * 16 + lr;
      if (MODE == 0) {
        const int sel = n >> 10;       // 0=Q 1=K 2=V (uniform per j)
        const int nn = n & 1023;
        const float bias = (sel == 0 ? b0 : sel == 1 ? b1 : b2)[nn];
        const int h = nn >> 6, dk = nn & 63;
        const int bidx = mrow >> 11;
        const int s = mrow & 2047;     // rows s..s+3 stay in same batch
        const int bh = bidx * Hh + h;
        if (sel == 2) {
          // V transposed: VT[bh][dk][s], 4 consecutive s -> one 8B store
          us4 pk;
#pragma unroll
          for (int r = 0; r < 4; ++r) pk[r] = f2bf(acc[i][j][r] + bias);
          *(us4*)&oVT[((size_t)bh * DKk + dk) * Ss + s] = pk;
        } else {
          ushort_t* dst = (sel == 0) ? oQ : oK;
          // Q: fold 1/sqrt(DK) * log2(e) so attn uses raw v_exp (exp2)
          const float mul = (sel == 0) ? 0.1803368842f : 1.0f;
#pragma unroll
          for (int r = 0; r < 4; ++r)
            dst[((size_t)bh * Ss + (s + r)) * DKk + dk] =
                f2bf((acc[i][j][r] + bias) * mul);
        }
      } else {
        const float bias = b0[n];
#pragma unroll
        for (int r = 0; r < 4; ++r)
          oF[(size_t)(mrow + r) * Dd + n] = acc[i][j][r] + bias;
      }
    }
  }
}

// ---------------------------------------------------------------- flash attention
// Merge of the two best measured structures: r6's verified per-wave math
// (swapped-operand QK^T, per-lane scalar softmax, register P, K=16 PV)
// with r2's 4-wave K-sharing and wave count.
//
// Block = 4 waves = one 64-row q-group g (wave w owns rows g*64+w*16..+15).
// K tile (64x64) double-buffered in LDS, staged by all 4 waves with
// global_load_lds (XOR-swizzled via pre-swizzled global source, r6-style);
// one __syncthreads per KV iteration (drains vmcnt -> stage complete, and
// fences the buffer swap). V read from global (L2) into registers before
// the softmax chain. 1024 blocks x 256 thr = 4096 waves.
//
// CU-balanced mapping: rounds r_=0..3 place g-sets {24+k,23-k,8+k,7-k} on
// the same CU -> sum(nt) = 66 for every k; heavy groups dispatch first.
__global__ __launch_bounds__(256, 4) void attn_k(const ushort_t* __restrict__ Qg,
                                                 const ushort_t* __restrict__ Kg,
                                                 const ushort_t* __restrict__ Vt,
                                                 ushort_t* __restrict__ AO) {
  __shared__ ushort_t Ks[2][64 * 64];   // 16 KB, double-buffered K tile
  const int tid = threadIdx.x, lane = tid & 63, wave = tid >> 6;
  const int bx = blockIdx.x;
  const int bh = bx & 31;                // bh&7 == XCD under round-robin
  const int r_ = bx >> 8;                // 0..3
  const int sub = (bx >> 5) & 7;         // 0..7
  const int g = (3 - r_) * 8 + ((r_ & 1) ? 7 - sub : sub);  // 0..31, heavy 1st
  const int lr = lane & 15, lg = lane >> 4;
  const ushort_t* Qp = Qg + (size_t)bh * Ss * DKk;
  const ushort_t* Kp = Kg + (size_t)bh * Ss * DKk;
  const ushort_t* Vp = Vt + (size_t)bh * DKk * Ss;
  const int s_row = lane >> 3;              // 0..7 within 8-row chunk
  const int s_slot = (lane & 7) ^ s_row;    // pre-swizzled 16B slot (rule 21)
  const int sw = lr & 7;
  const int q0 = g * 64 + wave * 16;        // wave's 16 q rows
  const int nt = g + 1;                     // KV tiles of 64

  // stage K tile t into Ks[buf]: wave stages rows wave*16..+15 (2 issues)
  auto stageK = [&](int t, int buf) {
    const int rb = wave * 16;
#pragma unroll
    for (int c = 0; c < 2; ++c)
      gload_lds16(Kp + (size_t)(t * 64 + rb + c * 8 + s_row) * DKk + s_slot * 8,
                  &Ks[buf][(rb + c * 8) * 64]);
  };

  stageK(0, 0);

  // Q fragment (B-operand of 16x16x32): row q0+lr, d = ks*32 + lg*8 ..+8
  bf16x8 qf[2];
#pragma unroll
  for (int ks = 0; ks < 2; ++ks)
    qf[ks] = *(const bf16x8*)&Qp[(size_t)(q0 + lr) * DKk + ks * 32 + lg * 8];

  f32x4 o[4] = {};   // O^T: o[dj][r] = O[q=lr][d = dj*16 + lg*4 + r]
  float m_ = -3e38f, l_ = 0.f;

  __syncthreads();  // K tile 0 staged (drains vmcnt)

  for (int t = 0; t < nt; ++t) {
    const int cb = t & 1;
    if (t + 1 < nt) stageK(t + 1, cb ^ 1);
    const int j0 = t * 64;
    const bool diag = (t == nt - 1);
    const int nct = diag ? wave + 1 : 4;   // diag k-subtile cap (dct = wave)

    // VT fragments (A-operand of 16x16x16): row d=dj*16+lr, s=j0+ct*16+lg*4
    bf16x4 vt4[4][4];
#pragma unroll
    for (int ct = 0; ct < 4; ++ct)
      if (ct < nct)
#pragma unroll
        for (int dj = 0; dj < 4; ++dj)
          vt4[dj][ct] = *(const bf16x4*)&Vp[(size_t)(dj * 16 + lr) * Ss + j0 +
                                            ct * 16 + lg * 4];

    // ---- S^T = K Q^T : sc[ct][r] = S[q=lr][k = ct*16 + lg*4 + r]
    f32x4 sc[4];
#pragma unroll
    for (int ct = 0; ct < 4; ++ct) {
      if (ct < nct) {
        const int krow = ct * 16 + lr;
        const bf16x8 k0v = *(const bf16x8*)&Ks[cb][krow * 64 + ((lg ^ sw) * 8)];
        const bf16x8 k1v =
            *(const bf16x8*)&Ks[cb][krow * 64 + (((4 | lg) ^ sw) * 8)];
        f32x4 z = {};
        z = __builtin_amdgcn_mfma_f32_16x16x32_bf16(k0v, qf[0], z, 0, 0, 0);
        z = __builtin_amdgcn_mfma_f32_16x16x32_bf16(k1v, qf[1], z, 0, 0, 0);
        sc[ct] = z;
      }
    }
    // causal element mask: only the diag's top k-subtile (ct == wave)
    if (diag) {
#pragma unroll
      for (int ct = 0; ct < 4; ++ct)
        if (ct == nct - 1)
#pragma unroll
          for (int r = 0; r < 4; ++r)
            if (lg * 4 + r > lr) sc[ct][r] = -1e30f;
    }

    // ---- online softmax, exp2 domain, per-lane scalar state (q = lr)
    float mx = -3e38f;
#pragma unroll
    for (int ct = 0; ct < 4; ++ct)
      if (ct < nct)
#pragma unroll
        for (int r = 0; r < 4; ++r) mx = fmaxf(mx, sc[ct][r]);
    mx = fmaxf(mx, __shfl_xor(mx, 16, 64));
    mx = fmaxf(mx, __shfl_xor(mx, 32, 64));
    const float mnew = fmaxf(m_, mx);
    const float fs = __builtin_exp2f(m_ - mnew);
    m_ = mnew;
    float ls = 0.f;
    bf16x4 pb[4];
#pragma unroll
    for (int ct = 0; ct < 4; ++ct) {
      if (ct < nct) {
        float p0 = __builtin_exp2f(sc[ct][0] - mnew);
        float p1 = __builtin_exp2f(sc[ct][1] - mnew);
        float p2 = __builtin_exp2f(sc[ct][2] - mnew);
        float p3 = __builtin_exp2f(sc[ct][3] - mnew);
        ls += (p0 + p1) + (p2 + p3);
        bf16x4 pbv;
        pbv[0] = (__bf16)p0;
        pbv[1] = (__bf16)p1;
        pbv[2] = (__bf16)p2;
        pbv[3] = (__bf16)p3;
        pb[ct] = pbv;
      }
    }
    ls += __shfl_xor(ls, 16, 64);
    ls += __shfl_xor(ls, 32, 64);
    l_ = l_ * fs + ls;
#pragma unroll
    for (int dj = 0; dj < 4; ++dj)
#pragma unroll
      for (int r = 0; r < 4; ++r) o[dj][r] *= fs;

    // ---- O^T += V^T P^T
    __builtin_amdgcn_s_setprio(1);
#pragma unroll
    for (int dj = 0; dj < 4; ++dj)
#pragma unroll
      for (int ct = 0; ct < 4; ++ct)
        if (ct < nct) mfma16(o[dj], vt4[dj][ct], pb[ct]);
    __builtin_amdgcn_s_setprio(0);

    __syncthreads();  // stage(t+1) complete (vmcnt0) + buffer handoff
  }

  // ---- normalize and write AO [b*S+s][h*64+d] bf16 (8B packed over d)
  const int bb = bh >> 4, hh = bh & 15;
  const float inv = 1.0f / l_;
#pragma unroll
  for (int dj = 0; dj < 4; ++dj) {
    us4 pk;
#pragma unroll
    for (int r = 0; r < 4; ++r) pk[r] = f2bf(o[dj][r] * inv);
    *(us4*)&AO[((size_t)bb * Ss + q0 + lr) * Dd + hh * 64 + dj * 16 + lg * 4] =
        pk;
  }
}

// ---------------------------------------------------------------- launch
extern "C" void kernel_launch(void* const* d_in, const int* in_sizes, int n_in,
                              void* d_out, int out_size, void* d_ws, size_t ws_size,
                              hipStream_t stream) {
  const float* x  = (const float*)d_in[0];
  // d_in[1] = causal mask (tril) — hardcoded in attn kernel
  const float* wq = (const float*)d_in[2];
  const float* bq = (const float*)d_in[3];
  const float* wk = (const float*)d_in[4];
  const float* bk = (const float*)d_in[5];
  const float* wv = (const float*)d_in[6];
  const float* bv = (const float*)d_in[7];
  const float* wo = (const float*)d_in[8];
  const float* bo = (const float*)d_in[9];

  ushort_t* ws   = (ushort_t*)d_ws;
  ushort_t* xb   = ws;                   // [4096][1024] bf16 (8MB), reused as AO
  ushort_t* wqkv = xb + 4096 * 1024;     // [3072][1024] bf16 (6MB)
  ushort_t* wob  = wqkv + 3072 * 1024;   // [1024][1024] bf16 (2MB)
  ushort_t* Qb   = wob + 1024 * 1024;    // [2,16,2048,64] bf16 (8MB)
  ushort_t* Kb   = Qb + 4194304;         // (8MB)
  ushort_t* VTb  = Kb + 4194304;         // [2,16,64,2048] bf16 (8MB)
  ushort_t* AOb  = xb;                   // reuse: x dead after QKV GEMM

  cast_k<<<2048, 256, 0, stream>>>(x, xb, 524288);
  cast_k<<<512, 256, 0, stream>>>(wq, wqkv, 131072);
  cast_k<<<512, 256, 0, stream>>>(wk, wqkv + 1048576, 131072);
  cast_k<<<512, 256, 0, stream>>>(wv, wqkv + 2097152, 131072);
  cast_k<<<512, 256, 0, stream>>>(wo, wob, 131072);

  gemm_k<0><<<dim3(24, 32), 256, 0, stream>>>(xb, wqkv, bq, bk, bv, Qb, Kb, VTb,
                                              nullptr);
  attn_k<<<1024, 256, 0, stream>>>(Qb, Kb, VTb, AOb);
  gemm_k<1><<<dim3(8, 32), 256, 0, stream>>>(AOb, wob, bo, nullptr, nullptr,
                                             nullptr, nullptr, nullptr,
                                             (float*)d_out);
}

// Round 10
// 151.168 us; speedup vs baseline: 1.7859x; 1.3367x over previous
//
#include <hip/hip_runtime.h>
#include <cstdint>
#include <cstddef>

// Problem dims
#define Bb 2
#define Ss 2048
#define Dd 1024
#define Hh 16
#define DKk 64

typedef unsigned short ushort_t;
typedef __bf16 bf16x8 __attribute__((ext_vector_type(8)));
typedef float f32x4 __attribute__((ext_vector_type(4)));
typedef unsigned short us8 __attribute__((ext_vector_type(8)));
typedef unsigned short us4 __attribute__((ext_vector_type(4)));

__device__ __forceinline__ ushort_t f2bf(float f) {
  __bf16 h = (__bf16)f;
  return __builtin_bit_cast(unsigned short, h);
}

// global -> LDS direct copy, 16B per lane. LDS dest must be wave-uniform;
// HW writes lane l's data at ldsbase + l*16.
__device__ __forceinline__ void gload_lds16(const void* g, void* l) {
  __builtin_amdgcn_global_load_lds(
      (__attribute__((address_space(1))) void*)(g),
      (__attribute__((address_space(3))) void*)(l),
      16, 0, 0);
}

// ---------------------------------------------------------------- cast fp32->bf16
__global__ __launch_bounds__(256) void cast_k(const float* __restrict__ s,
                                              ushort_t* __restrict__ d, int n8) {
  const int i = blockIdx.x * 256 + threadIdx.x;
  if (i >= n8) return;
  const float4* sp = (const float4*)s;
  float4 a = sp[2 * i], b = sp[2 * i + 1];
  us8 o;
  o[0] = f2bf(a.x); o[1] = f2bf(a.y); o[2] = f2bf(a.z); o[3] = f2bf(a.w);
  o[4] = f2bf(b.x); o[5] = f2bf(b.y); o[6] = f2bf(b.z); o[7] = f2bf(b.w);
  ((us8*)d)[i] = o;
}

// ---------------------------------------------------------------- GEMM
// y[m][n] = sum_k A[m][k] * W[n][k]  (both row-major, K contiguous)
// MODE 0: QKV projection. N=3072 (wq|wk|wv packed). Epilogue adds bias,
//         scales Q by 0.125*log2(e) (attn softmax runs in exp2 domain),
//         writes Q,K as [b,h,s,dk] bf16 and V transposed as VT [b,h,dk,s].
// MODE 1: output projection. N=1024. Epilogue adds bias, writes fp32 [m][n].
template <int MODE>
__global__ __launch_bounds__(256) void gemm_k(
    const ushort_t* __restrict__ A, const ushort_t* __restrict__ W,
    const float* __restrict__ b0, const float* __restrict__ b1,
    const float* __restrict__ b2,
    ushort_t* __restrict__ oQ, ushort_t* __restrict__ oK,
    ushort_t* __restrict__ oVT, float* __restrict__ oF) {
  constexpr int Kd = 1024;
  __shared__ ushort_t As[128 * 32];
  __shared__ ushort_t Bs[128 * 32];
  const int tid = threadIdx.x;
  const int lane = tid & 63;
  const int wave = tid >> 6;
  const int m0 = blockIdx.y * 128;
  const int n0 = blockIdx.x * 128;
  const int lr = lane & 15;
  const int lg = lane >> 4;
  const int srow = lane >> 2;        // staging row within 16-row segment
  const int scol = (lane & 3) * 8;   // staging col (elements)
  const int ar = (wave >> 1) * 64;   // wave's output row base in tile
  const int bc = (wave & 1) * 64;    // wave's output col base in tile

  f32x4 acc[4][4] = {};

  for (int kt = 0; kt < Kd / 32; ++kt) {
    const int k0 = kt * 32;
#pragma unroll
    for (int c = 0; c < 2; ++c) {
      const int seg = wave * 2 + c;  // 0..7, 16 rows (1KB) each
      const int row = seg * 16 + srow;
      gload_lds16(A + (size_t)(m0 + row) * Kd + k0 + scol, (char*)As + seg * 1024);
      gload_lds16(W + (size_t)(n0 + row) * Kd + k0 + scol, (char*)Bs + seg * 1024);
    }
    __syncthreads();  // drains vmcnt before barrier
    bf16x8 af[4], bfr[4];
#pragma unroll
    for (int i = 0; i < 4; ++i)
      af[i] = *(const bf16x8*)&As[(ar + i * 16 + lr) * 32 + lg * 8];
#pragma unroll
    for (int j = 0; j < 4; ++j)
      bfr[j] = *(const bf16x8*)&Bs[(bc + j * 16 + lr) * 32 + lg * 8];
#pragma unroll
    for (int i = 0; i < 4; ++i)
#pragma unroll
      for (int j = 0; j < 4; ++j)
        acc[i][j] = __builtin_amdgcn_mfma_f32_16x16x32_bf16(af[i], bfr[j],
                                                            acc[i][j], 0, 0, 0);
    __syncthreads();
  }

  // Epilogue. C/D layout: reg r -> row (lg*4 + r), col = lr  [m89-verified]
#pragma unroll
  for (int i = 0; i < 4; ++i) {
    const int mrow = m0 + ar + i * 16 + lg * 4;  // + r
#pragma unroll
    for (int j = 0; j < 4; ++j) {
      const int n = n0 + bc + j * 16 + lr;
      if (MODE == 0) {
        const int sel = n >> 10;       // 0=Q 1=K 2=V (uniform per j)
        const int nn = n & 1023;
        const float bias = (sel == 0 ? b0 : sel == 1 ? b1 : b2)[nn];
        const int h = nn >> 6, dk = nn & 63;
        const int bidx = mrow >> 11;
        const int s = mrow & 2047;     // rows s..s+3 stay in same batch
        const int bh = bidx * Hh + h;
        if (sel == 2) {
          // V transposed: VT[bh][dk][s], 4 consecutive s -> one 8B store
          us4 pk;
#pragma unroll
          for (int r = 0; r < 4; ++r) pk[r] = f2bf(acc[i][j][r] + bias);
          *(us4*)&oVT[((size_t)bh * DKk + dk) * Ss + s] = pk;
        } else {
          ushort_t* dst = (sel == 0) ? oQ : oK;
          // Q: fold 1/sqrt(DK) * log2(e) so attn uses raw v_exp (exp2)
          const float mul = (sel == 0) ? 0.1803368842f : 1.0f;
#pragma unroll
          for (int r = 0; r < 4; ++r)
            dst[((size_t)bh * Ss + (s + r)) * DKk + dk] =
                f2bf((acc[i][j][r] + bias) * mul);
        }
      } else {
        const float bias = b0[n];
#pragma unroll
        for (int r = 0; r < 4; ++r)
          oF[(size_t)(mrow + r) * Dd + n] = acc[i][j][r] + bias;
      }
    }
  }
}

// ---------------------------------------------------------------- flash attention
// v9 structure (4-wave shared K-LDS dbuf, light swapped softmax, balanced
// mapping) with the PV path reverted to v2's PROVEN K=32 16x16x32 MFMAs:
// the 16x16x16bf16_1k compat op (v6/v9) is suspected multi-pass/slow on
// gfx950 (v6: 2048 waves = v9: 4096 waves = ~134us -> pipe-throughput-bound
// on PV, not latency). P is relayed through a small per-wave LDS buffer
// (stride-72: <=2-way bank conflicts; 4x ds_write_b64, 2x ds_read_b128).
// s_setprio dropped (m190: hurts barrier-locked waves).
__global__ __launch_bounds__(256, 4) void attn_k(const ushort_t* __restrict__ Qg,
                                                 const ushort_t* __restrict__ Kg,
                                                 const ushort_t* __restrict__ Vt,
                                                 ushort_t* __restrict__ AO) {
  __shared__ ushort_t Ks[2][64 * 64];   // 16 KB, double-buffered K tile
  __shared__ ushort_t Pl[4][16 * 72];   // 9 KB, per-wave P (q-major, pad 72)
  const int tid = threadIdx.x, lane = tid & 63, wave = tid >> 6;
  const int bx = blockIdx.x;
  const int bh = bx & 31;                // bh&7 == XCD under round-robin
  const int r_ = bx >> 8;                // 0..3
  const int sub = (bx >> 5) & 7;         // 0..7
  const int g = (3 - r_) * 8 + ((r_ & 1) ? 7 - sub : sub);  // 0..31, heavy 1st
  const int lr = lane & 15, lg = lane >> 4;
  const ushort_t* Qp = Qg + (size_t)bh * Ss * DKk;
  const ushort_t* Kp = Kg + (size_t)bh * Ss * DKk;
  const ushort_t* Vp = Vt + (size_t)bh * DKk * Ss;
  ushort_t* P = Pl[wave];
  const int s_row = lane >> 3;              // 0..7 within 8-row chunk
  const int s_slot = (lane & 7) ^ s_row;    // pre-swizzled 16B slot (rule 21)
  const int sw = lr & 7;
  const int q0 = g * 64 + wave * 16;        // wave's 16 q rows
  const int nt = g + 1;                     // KV tiles of 64

  // stage K tile t into Ks[buf]: wave stages rows wave*16..+15 (2 issues)
  auto stageK = [&](int t, int buf) {
    const int rb = wave * 16;
#pragma unroll
    for (int c = 0; c < 2; ++c)
      gload_lds16(Kp + (size_t)(t * 64 + rb + c * 8 + s_row) * DKk + s_slot * 8,
                  &Ks[buf][(rb + c * 8) * 64]);
  };

  stageK(0, 0);

  // Q fragment (B-operand of 16x16x32): row q0+lr, d = ks*32 + lg*8 ..+8
  bf16x8 qf[2];
#pragma unroll
  for (int ks = 0; ks < 2; ++ks)
    qf[ks] = *(const bf16x8*)&Qp[(size_t)(q0 + lr) * DKk + ks * 32 + lg * 8];

  f32x4 o[4] = {};   // o[dj][r] = O[q = lg*4+r][d = dj*16 + lr]
  float m_ = -3e38f, l_ = 0.f;   // per-lane state for q = lr

  __syncthreads();  // K tile 0 staged (drains vmcnt)

  for (int t = 0; t < nt; ++t) {
    const int cb = t & 1;
    if (t + 1 < nt) stageK(t + 1, cb ^ 1);
    const int j0 = t * 64;
    const bool diag = (t == nt - 1);
    const int nct = diag ? wave + 1 : 4;   // diag k-subtile cap (dct = wave)

    // VT fragments (A-operand of 16x16x32): row d=dj*16+lr, s=j0+ksp*32+lg*8
    bf16x8 vt[4][2];
#pragma unroll
    for (int dj = 0; dj < 4; ++dj)
#pragma unroll
      for (int ksp = 0; ksp < 2; ++ksp)
        vt[dj][ksp] = *(const bf16x8*)&Vp[(size_t)(dj * 16 + lr) * Ss + j0 +
                                          ksp * 32 + lg * 8];

    // ---- S^T = K Q^T : sc[ct][r] = S[q=lr][k = ct*16 + lg*4 + r]
    f32x4 sc[4];
#pragma unroll
    for (int ct = 0; ct < 4; ++ct) {
      if (ct < nct) {
        const int krow = ct * 16 + lr;
        const bf16x8 k0v = *(const bf16x8*)&Ks[cb][krow * 64 + ((lg ^ sw) * 8)];
        const bf16x8 k1v =
            *(const bf16x8*)&Ks[cb][krow * 64 + (((4 | lg) ^ sw) * 8)];
        f32x4 z = {};
        z = __builtin_amdgcn_mfma_f32_16x16x32_bf16(k0v, qf[0], z, 0, 0, 0);
        z = __builtin_amdgcn_mfma_f32_16x16x32_bf16(k1v, qf[1], z, 0, 0, 0);
        sc[ct] = z;
      }
    }
    // causal element mask: only the diag's top k-subtile (ct == wave)
    if (diag) {
#pragma unroll
      for (int ct = 0; ct < 4; ++ct)
        if (ct == nct - 1)
#pragma unroll
          for (int r = 0; r < 4; ++r)
            if (lg * 4 + r > lr) sc[ct][r] = -1e30f;
    }

    // ---- online softmax, exp2 domain, per-lane scalar state (q = lr)
    float mx = -3e38f;
#pragma unroll
    for (int ct = 0; ct < 4; ++ct)
      if (ct < nct)
#pragma unroll
        for (int r = 0; r < 4; ++r) mx = fmaxf(mx, sc[ct][r]);
    mx = fmaxf(mx, __shfl_xor(mx, 16, 64));
    mx = fmaxf(mx, __shfl_xor(mx, 32, 64));
    const float mnew = fmaxf(m_, mx);
    const float fs = __builtin_exp2f(m_ - mnew);
    m_ = mnew;
    float ls = 0.f;
#pragma unroll
    for (int ct = 0; ct < 4; ++ct) {
      if (ct < nct) {
        float p0 = __builtin_exp2f(sc[ct][0] - mnew);
        float p1 = __builtin_exp2f(sc[ct][1] - mnew);
        float p2 = __builtin_exp2f(sc[ct][2] - mnew);
        float p3 = __builtin_exp2f(sc[ct][3] - mnew);
        ls += (p0 + p1) + (p2 + p3);
        us4 pk;
        pk[0] = f2bf(p0); pk[1] = f2bf(p1); pk[2] = f2bf(p2); pk[3] = f2bf(p3);
        // P[q = lr][k = ct*16 + lg*4 .. +4]  (one 8B write)
        *(us4*)&P[lr * 72 + ct * 16 + lg * 4] = pk;
      } else {
        us4 zz = {};  // masked k-subtile on diag: exact zeros
        *(us4*)&P[lr * 72 + ct * 16 + lg * 4] = zz;
      }
    }
    ls += __shfl_xor(ls, 16, 64);
    ls += __shfl_xor(ls, 32, 64);
    l_ = l_ * fs + ls;

    // ---- rescale O (fs is for q=lr; o rows are q=lg*4+r -> need fs there)
    // fetch fs for q' = lg*4+r via bpermute (all lg replicas hold same value)
    float fso[4];
#pragma unroll
    for (int r = 0; r < 4; ++r) fso[r] = __shfl(fs, lg * 4 + r, 64);
#pragma unroll
    for (int dj = 0; dj < 4; ++dj)
#pragma unroll
      for (int r = 0; r < 4; ++r) o[dj][r] *= fso[r];

    // LDS write->read ordering within the wave
    asm volatile("s_waitcnt lgkmcnt(0)" ::: "memory");
    // ---- O += P V : A-op = P rows q (bf16x8 from LDS), B-op = vt
    bf16x8 pa[2];
#pragma unroll
    for (int ksp = 0; ksp < 2; ++ksp)
      pa[ksp] = *(const bf16x8*)&P[lr * 72 + ksp * 32 + lg * 8];
#pragma unroll
    for (int dj = 0; dj < 4; ++dj)
#pragma unroll
      for (int ksp = 0; ksp < 2; ++ksp)
        o[dj] = __builtin_amdgcn_mfma_f32_16x16x32_bf16(pa[ksp], vt[dj][ksp],
                                                        o[dj], 0, 0, 0);

    __syncthreads();  // stage(t+1) complete (vmcnt0) + buffer handoff
  }

  // ---- normalize and write AO [b*S+s][h*64+d] bf16
  const int bb = bh >> 4, hh = bh & 15;
#pragma unroll
  for (int r = 0; r < 4; ++r) {
    const float lq = __shfl(l_, lg * 4 + r, 64);  // l for q = lg*4+r
    const float inv = 1.0f / lq;
    const size_t m = (size_t)bb * Ss + q0 + lg * 4 + r;
#pragma unroll
    for (int dj = 0; dj < 4; ++dj)
      AO[m * Dd + hh * 64 + dj * 16 + lr] = f2bf(o[dj][r] * inv);
  }
}

// ---------------------------------------------------------------- launch
extern "C" void kernel_launch(void* const* d_in, const int* in_sizes, int n_in,
                              void* d_out, int out_size, void* d_ws, size_t ws_size,
                              hipStream_t stream) {
  const float* x  = (const float*)d_in[0];
  // d_in[1] = causal mask (tril) — hardcoded in attn kernel
  const float* wq = (const float*)d_in[2];
  const float* bq = (const float*)d_in[3];
  const float* wk = (const float*)d_in[4];
  const float* bk = (const float*)d_in[5];
  const float* wv = (const float*)d_in[6];
  const float* bv = (const float*)d_in[7];
  const float* wo = (const float*)d_in[8];
  const float* bo = (const float*)d_in[9];

  ushort_t* ws   = (ushort_t*)d_ws;
  ushort_t* xb   = ws;                   // [4096][1024] bf16 (8MB), reused as AO
  ushort_t* wqkv = xb + 4096 * 1024;     // [3072][1024] bf16 (6MB)
  ushort_t* wob  = wqkv + 3072 * 1024;   // [1024][1024] bf16 (2MB)
  ushort_t* Qb   = wob + 1024 * 1024;    // [2,16,2048,64] bf16 (8MB)
  ushort_t* Kb   = Qb + 4194304;         // (8MB)
  ushort_t* VTb  = Kb + 4194304;         // [2,16,64,2048] bf16 (8MB)
  ushort_t* AOb  = xb;                   // reuse: x dead after QKV GEMM

  cast_k<<<2048, 256, 0, stream>>>(x, xb, 524288);
  cast_k<<<512, 256, 0, stream>>>(wq, wqkv, 131072);
  cast_k<<<512, 256, 0, stream>>>(wk, wqkv + 1048576, 131072);
  cast_k<<<512, 256, 0, stream>>>(wv, wqkv + 2097152, 131072);
  cast_k<<<512, 256, 0, stream>>>(wo, wob, 131072);

  gemm_k<0><<<dim3(24, 32), 256, 0, stream>>>(xb, wqkv, bq, bk, bv, Qb, Kb, VTb,
                                              nullptr);
  attn_k<<<1024, 256, 0, stream>>>(Qb, Kb, VTb, AOb);
  gemm_k<1><<<dim3(8, 32), 256, 0, stream>>>(AOb, wob, bo, nullptr, nullptr,
                                             nullptr, nullptr, nullptr,
                                             (float*)d_out);
}